// Round 7
// baseline (248.477 us; speedup 1.0000x reference)
//
#include <hip/hip_runtime.h>

#define NFREQ 2049
#define L1LEN 1025
#define L1STRIDE 1026
#define L2LEN 513

typedef short v8s  __attribute__((ext_vector_type(8)));
typedef float v16f __attribute__((ext_vector_type(16)));
typedef unsigned short ushort_t;
typedef unsigned int uint_t;

// ---------------- workspace layout (float offsets) ----------------
#define OFF_FFT     0ull          // 524544
#define OFF_TWID    524544ull     // 2048
#define OFF_PTW     526592ull     // 4352
#define OFF_WIN     530944ull     // 4096
#define OFF_PART    535040ull     // 540672
#define OFF_TW      1075712ull    // 256
#define OFF_TI      1075968ull    // 256 (ints)
#define OFF_SRWLOG  1076224ull    // 256
#define OFF_W2HF    1076480ull    // 5120  (ushort 10240, fragment-packed)
#define OFF_W2LF    1081600ull    // 5120
#define OFF_W2F     1086720ull    // 163840 (ushort 327680, fragment-packed)
#define OFF_W3F     1250560ull    // 196608 (ushort 393216, fragment-packed)
#define OFF_A       1447168ull    // E1u[2] (ushort 2*8404992)
#define OFF_E2U     9852160ull    // FINAL f32 [b][o][q] (8404992) -- old E2u region
// total 18,257,152 floats ~ 69.6 MiB

#define E1U_K_STRIDE 8404992      // ushort elements per k (128*64*1026)

__device__ __forceinline__ float relu_f(float x) { return fmaxf(x, 0.0f); }
__device__ __forceinline__ int   rfl_i(int v)   { return __builtin_amdgcn_readfirstlane(v); }
__device__ __forceinline__ float rfl_f(float v) { return __uint_as_float((unsigned)__builtin_amdgcn_readfirstlane((int)__float_as_uint(v))); }
__device__ __forceinline__ ushort_t f2bf(float x) {
    unsigned u = __float_as_uint(x);
    unsigned r = (u + 0x7FFFu + ((u >> 16) & 1u)) >> 16;   // RNE
    return (ushort_t)r;
}
__device__ __forceinline__ float bf2f(ushort_t h) { return __uint_as_float(((unsigned)h) << 16); }

// ---------------- init: tables + zero aux + fragment-pack weights ----------------
__global__ void init_kernel(float* SRWLOG, float* TWID, float* PTW, float* WIN,
                            ushort_t* W2HF, ushort_t* W2LF, ushort_t* W2F, ushort_t* W3F,
                            const float* g_w2, const float* ew2, const float* ew3) {
    const float PI = 3.14159265358979323846f;
    int tid = blockIdx.x * blockDim.x + threadIdx.x;
    int stride = gridDim.x * blockDim.x;
    for (int i = tid; i < 16; i += stride) SRWLOG[i] = 0.0f;
    for (int j = tid; j < 1024; j += stride) {
        float a = PI * (float)j / 1024.0f;
        TWID[2 * j] = cosf(a);
        TWID[2 * j + 1] = -sinf(a);
    }
    for (int k = tid; k < 2049; k += stride) {
        float a = PI * (float)k / 2048.0f;
        PTW[2 * k] = cosf(a);
        PTW[2 * k + 1] = sinf(a);
    }
    for (int n = tid; n < 4096; n += stride) {
        WIN[n] = 0.5f * (1.0f - cosf(2.0f * PI * (float)n / 4096.0f));
    }
    // g_w2 (64,32,5) -> W2HF/W2LF frag id=((t5*2+tile)*2+ks)
    for (int i = tid; i < 10240; i += stride) {
        int j = i & 7;
        int lane = (i >> 3) & 63;
        int ks = (i >> 9) & 1;
        int tile = (i >> 10) & 1;
        int t = i >> 11;
        int o = tile * 32 + (lane & 31);
        int c = ks * 16 + (lane >> 5) * 8 + j;
        float w = g_w2[o * 160 + c * 5 + t];
        ushort_t h = f2bf(w);
        W2HF[i] = h;
        W2LF[i] = f2bf(w - bf2f(h));
    }
    // ew2 (8,128,64,5) -> W2F frag id=(((e*5+t5)*4+w)*4+ks)
    for (int i = tid; i < 327680; i += stride) {
        int j = i & 7;
        int lane = (i >> 3) & 63;
        int ks = (i >> 9) & 3;
        int w = (i >> 11) & 3;
        int t = (i >> 13) % 5;
        int e = i / 40960;
        int o = w * 32 + (lane & 31);
        int c = ks * 16 + (lane >> 5) * 8 + j;
        W2F[i] = f2bf(ew2[((e * 128 + o) * 64 + c) * 5 + t]);
    }
    // ew3 (8,128,128,3) -> W3F frag id=(((e*3+t3)*4+w)*8+ks)
    for (int i = tid; i < 393216; i += stride) {
        int j = i & 7;
        int lane = (i >> 3) & 63;
        int ks = (i >> 9) & 7;
        int w = (i >> 12) & 3;
        int t = (i >> 14) % 3;
        int e = i / 49152;
        int o = w * 32 + (lane & 31);
        int c = ks * 16 + (lane >> 5) * 8 + j;
        W3F[i] = f2bf(ew3[((e * 128 + o) * 128 + c) * 3 + t]);
    }
}

// ---------------- windowed rfft(4096) via 2048-pt complex FFT (1024 threads) ----------------
__global__ __launch_bounds__(1024) void fft_kernel(const float* __restrict__ x,
                                                   const float* __restrict__ TWID,
                                                   const float* __restrict__ PTW,
                                                   const float* __restrict__ WIN,
                                                   float* __restrict__ FFT) {
    __shared__ float re[2048];
    __shared__ float im[2048];
    int b = blockIdx.x, t = threadIdx.x;
    const float* xb = x + b * 4096;
    for (int i = t; i < 2048; i += 1024) {
        int j = (int)(__brev((unsigned)i) >> 21);   // 11-bit reversal
        re[i] = xb[2 * j] * WIN[2 * j];
        im[i] = xb[2 * j + 1] * WIN[2 * j + 1];
    }
    for (int s = 1; s <= 11; ++s) {
        __syncthreads();
        int half = 1 << (s - 1);
        int shift = 11 - s;
        int bf = t;
        {
            int grp = bf >> (s - 1);
            int pos = bf & (half - 1);
            int i1 = (grp << s) + pos;
            int i2 = i1 + half;
            int j = pos << shift;
            float wr = TWID[2 * j], wi = TWID[2 * j + 1];
            float ar = re[i2], ai = im[i2];
            float tr = wr * ar - wi * ai;
            float ti = wr * ai + wi * ar;
            float br = re[i1], bi = im[i1];
            re[i2] = br - tr; im[i2] = bi - ti;
            re[i1] = br + tr; im[i1] = bi + ti;
        }
    }
    __syncthreads();
    const float scale = 1.0f / 64.0f;
    for (int k = t; k <= 2048; k += 1024) {
        int k1 = k & 2047;
        int k2 = (2048 - k) & 2047;
        float zr = re[k1], zi = im[k1];
        float yr = re[k2], yi = im[k2];
        float Er = 0.5f * (zr + yr), Ei = 0.5f * (zi - yi);
        float Or = 0.5f * (zi + yi), Oi = 0.5f * (yr - zr);
        float c2 = PTW[2 * k], s3 = PTW[2 * k + 1];
        FFT[b * 4098 + k]        = (Er + c2 * Or + s3 * Oi) * scale;
        FFT[b * 4098 + 2049 + k] = (Ei + c2 * Oi - s3 * Or) * scale;
    }
}

// ---------------- fused gate conv1 + conv2 (split-precision MFMA) + partial mean-pool ----------------
__global__ __launch_bounds__(256) void g12_kernel(const float* __restrict__ FFT,
                                                  const float* __restrict__ g_w1, const float* __restrict__ g_b1,
                                                  const ushort_t* __restrict__ W2HF, const ushort_t* __restrict__ W2LF,
                                                  const float* __restrict__ g_b2,
                                                  float* __restrict__ PART) {
    __shared__ float fx[2][72];
    __shared__ float w1S[320];
    __shared__ float b1S[32];
    __shared__ __align__(16) char un[17408];
    ushort_t (*xh)[40] = (ushort_t (*)[40])un;            // [68][40] = 5440B
    ushort_t (*xl)[40] = (ushort_t (*)[40])(un + 5440);   // [68][40] = 5440B
    float (*red)[68]  = (float (*)[68])un;                // [64][68] = 17408B (aliases xh/xl after MFMA)
    int b = blockIdx.y;
    int q0 = blockIdx.x * 64;
    int t = threadIdx.x;
    for (int i = t; i < 352; i += 256) {
        if (i < 320) w1S[i] = g_w1[i];
        else b1S[i - 320] = g_b1[i - 320];
    }
    {
        const float* fb = FFT + b * 4098;
        for (int i = t; i < 144; i += 256) {
            int ch = i / 72, u = i % 72;
            int P = q0 - 4 + u;
            fx[ch][u] = (P >= 0 && P < NFREQ) ? fb[ch * NFREQ + P] : 0.0f;
        }
    }
    __syncthreads();
    // ---- conv1: 17 row-groups x 32 ch; weights in regs; window via float4 ----
    {
        int c = t & 31;
        float bias = b1S[c];
        float wr[10];
        #pragma unroll
        for (int j = 0; j < 10; ++j) wr[j] = w1S[c * 10 + j];
        for (int i = t; i < 544; i += 256) {
            int g4 = (i >> 5) << 2;                       // base row, multiple of 4
            float4 x00 = *(const float4*)&fx[0][g4];
            float4 x01 = *(const float4*)&fx[0][g4 + 4];
            float4 x10 = *(const float4*)&fx[1][g4];
            float4 x11 = *(const float4*)&fx[1][g4 + 4];
            float xa[8] = {x00.x, x00.y, x00.z, x00.w, x01.x, x01.y, x01.z, x01.w};
            float xb_[8] = {x10.x, x10.y, x10.z, x10.w, x11.x, x11.y, x11.z, x11.w};
            #pragma unroll
            for (int rr = 0; rr < 4; ++rr) {
                int row = g4 + rr;
                int pos = q0 - 2 + row;
                ushort_t h = 0, l = 0;
                if (pos >= 0 && pos < NFREQ) {
                    float a = bias;
                    #pragma unroll
                    for (int tt = 0; tt < 5; ++tt) a = fmaf(xa[rr + tt], wr[tt], a);
                    #pragma unroll
                    for (int tt = 0; tt < 5; ++tt) a = fmaf(xb_[rr + tt], wr[5 + tt], a);
                    a = relu_f(a);
                    h = f2bf(a);
                    l = f2bf(a - bf2f(h));
                }
                xh[row][c] = h;
                xl[row][c] = l;
            }
        }
    }
    __syncthreads();
    int lane = t & 63;
    int w = rfl_i(t >> 6);
    int tile = w & 1;
    int qh = w >> 1;
    int n = lane & 31;
    int kg = lane >> 5;
    v16f acc;
    #pragma unroll
    for (int i = 0; i < 16; ++i) acc[i] = 0.0f;
    #pragma unroll
    for (int t5 = 0; t5 < 5; ++t5) {
        int row = qh * 32 + n + t5;
        #pragma unroll
        for (int ks = 0; ks < 2; ++ks) {
            int c0 = ks * 16 + kg * 8;
            v8s Ah = *(const v8s*)(W2HF + (((t5 * 2 + tile) * 2 + ks) << 9) + lane * 8);
            v8s Al = *(const v8s*)(W2LF + (((t5 * 2 + tile) * 2 + ks) << 9) + lane * 8);
            v8s Bh = *(const v8s*)&xh[row][c0];
            v8s Bl = *(const v8s*)&xl[row][c0];
            acc = __builtin_amdgcn_mfma_f32_32x32x16_bf16(Ah, Bh, acc, 0, 0, 0);
            acc = __builtin_amdgcn_mfma_f32_32x32x16_bf16(Ah, Bl, acc, 0, 0, 0);
            acc = __builtin_amdgcn_mfma_f32_32x32x16_bf16(Al, Bh, acc, 0, 0, 0);
        }
    }
    __syncthreads();   // xh/xl dead -> red
    {
        int q = q0 + qh * 32 + n;
        bool valid = (q < NFREQ);
        #pragma unroll
        for (int r = 0; r < 16; ++r) {
            int m = (r & 3) + 8 * (r >> 2) + 4 * kg;
            int o = tile * 32 + m;
            red[o][qh * 32 + n] = valid ? relu_f(acc[r] + g_b2[o]) : 0.0f;
        }
    }
    __syncthreads();
    // ---- transpose reduce: thread t sums red[t>>2][(t&3)*16 .. +16) ----
    {
        int o = t >> 2;
        int qq = t & 3;
        float s = 0.0f;
        #pragma unroll
        for (int u = 0; u < 4; ++u) {
            float4 vv = *(const float4*)&red[o][qq * 16 + u * 4];
            s += vv.x + vv.y + vv.z + vv.w;
        }
        s += __shfl_xor(s, 1, 64);
        s += __shfl_xor(s, 2, 64);
        if (qq == 0) PART[(b * 64 + o) * 66 + blockIdx.x] = s;
    }
}

// ---------------- router MLP + softmax + top2 + aux partials ----------------
__global__ __launch_bounds__(128) void mlp_kernel(const float* __restrict__ PART,
                                                  const float* __restrict__ m_w1, const float* __restrict__ m_b1,
                                                  const float* __restrict__ m_w2, const float* __restrict__ m_b2,
                                                  float* TW, int* TI, float* SRWLOG) {
    __shared__ float pooledS[64];
    __shared__ float hid[128];
    __shared__ float lgS[8];
    __shared__ float rwS[8];
    int b = blockIdx.x, t = threadIdx.x;
    if (t < 64) {
        float s = 0.0f;
        const float* pp = PART + (b * 64 + t) * 66;
        for (int blk = 0; blk < 33; ++blk) s += pp[blk];
        pooledS[t] = s;
    }
    __syncthreads();
    const float inv = 1.0f / 2049.0f;
    {
        float h = m_b1[t];
        for (int c = 0; c < 64; ++c)
            h = fmaf(pooledS[c] * inv, m_w1[t * 64 + c], h);
        hid[t] = relu_f(h);
    }
    __syncthreads();
    if (t < 8) {
        float lg = m_b2[t];
        for (int j = 0; j < 128; ++j) lg = fmaf(hid[j], m_w2[t * 128 + j], lg);
        lgS[t] = lg;
    }
    __syncthreads();
    if (t == 0) {
        float mx = lgS[0];
        for (int e = 1; e < 8; ++e) mx = fmaxf(mx, lgS[e]);
        float s = 0.0f, ex[8];
        for (int e = 0; e < 8; ++e) { ex[e] = expf(lgS[e] - mx); s += ex[e]; }
        for (int e = 0; e < 8; ++e) rwS[e] = ex[e] / s;
        int i1 = 0;
        for (int e = 1; e < 8; ++e) if (rwS[e] > rwS[i1]) i1 = e;
        int i2 = (i1 == 0) ? 1 : 0;
        for (int e = 0; e < 8; ++e) if (e != i1 && rwS[e] > rwS[i2]) i2 = e;
        float t0 = rwS[i1], t1 = rwS[i2], sm = t0 + t1;
        TW[b * 2] = t0 / sm; TW[b * 2 + 1] = t1 / sm;
        TI[b * 2] = i1; TI[b * 2 + 1] = i2;
    }
    __syncthreads();
    if (t < 8) {
        atomicAdd(&SRWLOG[t], rwS[t]);
        atomicAdd(&SRWLOG[8 + t], lgS[t]);
    }
}

// ---------------- expert conv1: (2->64, k=7, s=2, p=3), bf16 out, row stride 1026 ----------------
__global__ __launch_bounds__(256) void e1_kernel(const float* __restrict__ FFT,
                                                 const float* __restrict__ ew1, const float* __restrict__ eb1,
                                                 const int* __restrict__ TI, ushort_t* __restrict__ E1u) {
    __shared__ float xs[2][520];
    int r0 = blockIdx.x * 256;
    int b = blockIdx.y;
    int k = blockIdx.z;
    int t = threadIdx.x;
    int e = rfl_i(TI[b * 2 + k]);
    int lo = 2 * r0 - 3;
    const float* fb = FFT + b * 4098;
    for (int i = t; i < 2 * 520; i += 256) {
        int ch = i / 520, off = i % 520;
        int pos = lo + off;
        xs[ch][off] = (pos >= 0 && pos < NFREQ) ? fb[ch * NFREQ + pos] : 0.0f;
    }
    __syncthreads();
    int r = r0 + t;
    if (r >= L1LEN) return;
    float xv[14];
    #pragma unroll
    for (int ch = 0; ch < 2; ++ch)
        #pragma unroll
        for (int tt = 0; tt < 7; ++tt)
            xv[ch * 7 + tt] = xs[ch][2 * t + tt];
    const float* wb = ew1 + e * 64 * 14;
    const float* bb = eb1 + e * 64;
    ushort_t* outb = E1u + (size_t)k * E1U_K_STRIDE + (size_t)b * 64 * L1STRIDE + r;
    bool last = (r == L1LEN - 1);
    for (int o = 0; o < 64; ++o) {
        float a = bb[o];
        const float* w = wb + o * 14;
        #pragma unroll
        for (int j = 0; j < 14; ++j)
            a = fmaf(xv[j], w[j], a);
        outb[o * L1STRIDE] = f2bf(relu_f(a));
        if (last) outb[o * L1STRIDE + 1] = 0;   // zero pad slot 1025 for e23's uint loads
    }
}

// ---------------- FUSED expert conv2 + conv3: E1 -> FINAL f32 [b][o][q] ----------------
// r7: LDS 46.2KB -> 37.5KB (row-tile 2 remapped to rows 34..65 instead of 64..95;
// overlap rows recomputed identically, stores gated) => 4 blocks/CU, 32 waves/CU
// static (was 3/24). r6 counters showed MFMA+VALU ~= occupancy (always-busy), so
// occupancy is the throughput lever here.
__global__ __launch_bounds__(512) void e23_kernel(const ushort_t* __restrict__ E1u,
                                                  const ushort_t* __restrict__ W2F, const float* __restrict__ eb2,
                                                  const ushort_t* __restrict__ W3F, const float* __restrict__ eb3,
                                                  const int* __restrict__ TI, const float* __restrict__ TW,
                                                  float* __restrict__ FINAL) {
    __shared__ __align__(16) ushort_t xe[68][72];   // E1 even positions (pairs 0..67, base 2q0-4)
    __shared__ __align__(16) ushort_t xo[68][72];   // E1 odd positions
    __shared__ __align__(16) ushort_t xT[66][136];  // E2 tile rows q0-1 .. q0+64 (bf16)
    int b = blockIdx.x;
    int q0 = blockIdx.y * 64;
    int t = threadIdx.x;
    int lane = t & 63;
    int w = rfl_i(t >> 6);        // 0..7
    int n = lane & 31;
    int kg = lane >> 5;
    int ow3 = w & 3;              // conv3 o-tile
    int qh3 = w >> 2;             // conv3 q-half
    float res[16];
    #pragma unroll
    for (int i = 0; i < 16; ++i) res[i] = 0.0f;
    for (int k = 0; k < 2; ++k) {
        int e = rfl_i(TI[b * 2 + k]);
        float wk = rfl_f(TW[b * 2 + k]);
        const ushort_t* E1k = E1u + (size_t)k * E1U_K_STRIDE;
        __syncthreads();   // prev iteration's xe/xT reads done
        // ---- stage E1: 64 c x 68 row-pairs, base position 2q0-4 ----
        for (int i = t; i < 64 * 68; i += 512) {
            int c = i / 68, j = i - c * 68;
            int p = 2 * q0 - 4 + 2 * j;
            uint_t v = 0;
            if (p >= 0 && p < L1LEN)             // p==1024 ok: slot 1025 is zeroed pad
                v = *(const uint_t*)(E1k + (size_t)(b * 64 + c) * L1STRIDE + p);
            xe[j][c] = (ushort_t)(v & 0xFFFFu);
            xo[j][c] = (ushort_t)(v >> 16);
        }
        __syncthreads();
        // ---- conv2 MFMA: 12 tiles; rt base rows {0, 32, 34} (rt2 overlaps rt1 by 30,
        //      recomputing identical values; only its rows 64,65 are newly stored) ----
        #pragma unroll
        for (int rep = 0; rep < 2; ++rep) {
            int tid = w + rep * 8;
            if (tid < 12) {
                int rt = tid >> 2, ot = tid & 3;
                int rbase = (rt == 2) ? 34 : rt * 32;
                v16f acc;
                #pragma unroll
                for (int i = 0; i < 16; ++i) acc[i] = 0.0f;
                #pragma unroll
                for (int t5 = 0; t5 < 5; ++t5) {
                    int roff = t5 >> 1;
                    const ushort_t (*sel)[72] = (t5 & 1) ? xo : xe;
                    const ushort_t* wfrag = W2F + ((((e * 5 + t5) * 4 + ot) * 4) << 9) + lane * 8;
                    #pragma unroll
                    for (int ks = 0; ks < 4; ++ks) {
                        int c0 = ks * 16 + kg * 8;
                        v8s a = *(const v8s*)(wfrag + (ks << 9));
                        v8s bb = *(const v8s*)&sel[rbase + n + roff][c0];
                        acc = __builtin_amdgcn_mfma_f32_32x32x16_bf16(a, bb, acc, 0, 0, 0);
                    }
                }
                int jj = rbase + n;
                if (rt < 2 || n >= 30) {             // skip duplicate stores (rows 34..63 of rt2)
                    int qp = q0 - 1 + jj;
                    bool ok = (qp >= 0 && qp < L2LEN);   // conv3 pad rows must be ZERO
                    #pragma unroll
                    for (int g = 0; g < 4; ++g) {
                        int ob = ot * 32 + 8 * g + 4 * kg;
                        uint_t p0 = 0, p1 = 0;
                        if (ok) {
                            p0 = (uint_t)f2bf(relu_f(acc[4 * g + 0] + eb2[e * 128 + ob + 0]))
                               | ((uint_t)f2bf(relu_f(acc[4 * g + 1] + eb2[e * 128 + ob + 1])) << 16);
                            p1 = (uint_t)f2bf(relu_f(acc[4 * g + 2] + eb2[e * 128 + ob + 2]))
                               | ((uint_t)f2bf(relu_f(acc[4 * g + 3] + eb2[e * 128 + ob + 3])) << 16);
                        }
                        uint2 v; v.x = p0; v.y = p1;
                        *(uint2*)&xT[jj][ob] = v;
                    }
                }
            }
        }
        __syncthreads();
        // ---- conv3 MFMA: wave = (ow3, qh3), accumulate weighted into res ----
        {
            v16f a0;
            #pragma unroll
            for (int i = 0; i < 16; ++i) a0[i] = 0.0f;
            #pragma unroll
            for (int t3 = 0; t3 < 3; ++t3) {
                const ushort_t* wfrag = W3F + ((((e * 3 + t3) * 4 + ow3) * 8) << 9) + lane * 8;
                #pragma unroll
                for (int ks = 0; ks < 8; ++ks) {
                    int c0 = ks * 16 + kg * 8;
                    v8s a = *(const v8s*)(wfrag + (ks << 9));
                    v8s bb = *(const v8s*)&xT[qh3 * 32 + n + t3][c0];
                    a0 = __builtin_amdgcn_mfma_f32_32x32x16_bf16(a, bb, a0, 0, 0, 0);
                }
            }
            #pragma unroll
            for (int r = 0; r < 16; ++r) {
                int m = (r & 3) + 8 * (r >> 2) + 4 * kg;
                float bias = eb3[e * 128 + ow3 * 32 + m];
                res[r] += relu_f(a0[r] + bias) * wk;
            }
        }
    }
    // ---- store FINAL[b][o][q] directly from C-frags ----
    int q = q0 + qh3 * 32 + n;
    if (q < L2LEN) {
        float* Fb = FINAL + (size_t)b * 128 * 513;
        #pragma unroll
        for (int r = 0; r < 16; ++r) {
            int m = (r & 3) + 8 * (r >> 2) + 4 * kg;
            Fb[(ow3 * 32 + m) * 513 + q] = res[r];
        }
    }
}

// ---------------- adaptive max-pool (one thread per output) + aux epilogue ----------------
__global__ __launch_bounds__(256) void pool_kernel(const float* __restrict__ FINAL,
                                                   const float* __restrict__ SRWLOG,
                                                   float* __restrict__ out) {
    if (blockIdx.x == 0 && threadIdx.x == 0) {
        float a = 0.0f;
        for (int e = 0; e < 8; ++e)
            a += (SRWLOG[e] / 128.0f) * (SRWLOG[8 + e] / 128.0f);
        out[4194304] = 0.01f * 8.0f * a;
    }
    int idx = blockIdx.x * 256 + threadIdx.x;     // 4,194,304 outputs
    int j = idx & 255;
    int row = idx >> 8;                           // b*128 + o
    const float* f = FINAL + (size_t)row * 513;
    int s = (513 * j) >> 8;
    int e_ = (513 * (j + 1) + 255) >> 8;          // <= 513
    float m = f[s];
    for (int p = s + 1; p < e_; ++p) m = fmaxf(m, f[p]);
    out[idx] = m;
}

extern "C" void kernel_launch(void* const* d_in, const int* in_sizes, int n_in,
                              void* d_out, int out_size, void* d_ws, size_t ws_size,
                              hipStream_t stream) {
    const float* x    = (const float*)d_in[0];
    const float* g_w1 = (const float*)d_in[1];
    const float* g_b1 = (const float*)d_in[2];
    const float* g_w2 = (const float*)d_in[3];
    const float* g_b2 = (const float*)d_in[4];
    const float* m_w1 = (const float*)d_in[5];
    const float* m_b1 = (const float*)d_in[6];
    const float* m_w2 = (const float*)d_in[7];
    const float* m_b2 = (const float*)d_in[8];
    const float* ew1  = (const float*)d_in[9];
    const float* eb1  = (const float*)d_in[10];
    const float* ew2  = (const float*)d_in[11];
    const float* eb2  = (const float*)d_in[12];
    const float* ew3  = (const float*)d_in[13];
    const float* eb3  = (const float*)d_in[14];

    float* ws     = (float*)d_ws;
    float* FFT    = ws + OFF_FFT;
    float* TWID   = ws + OFF_TWID;
    float* PTW    = ws + OFF_PTW;
    float* WIN    = ws + OFF_WIN;
    float* PART   = ws + OFF_PART;
    float* TW     = ws + OFF_TW;
    int*   TI     = (int*)(ws + OFF_TI);
    float* SRWLOG = ws + OFF_SRWLOG;
    ushort_t* W2HF = (ushort_t*)(ws + OFF_W2HF);
    ushort_t* W2LF = (ushort_t*)(ws + OFF_W2LF);
    ushort_t* W2F  = (ushort_t*)(ws + OFF_W2F);
    ushort_t* W3F  = (ushort_t*)(ws + OFF_W3F);
    ushort_t* E1u = (ushort_t*)(ws + OFF_A);
    float* FINAL  = ws + OFF_E2U;               // old E2u region (dead after fusion)
    float* out    = (float*)d_out;

    init_kernel<<<512, 256, 0, stream>>>(SRWLOG, TWID, PTW, WIN, W2HF, W2LF, W2F, W3F, g_w2, ew2, ew3);
    fft_kernel<<<128, 1024, 0, stream>>>(x, TWID, PTW, WIN, FFT);
    g12_kernel<<<dim3(33, 128), 256, 0, stream>>>(FFT, g_w1, g_b1, W2HF, W2LF, g_b2, PART);
    mlp_kernel<<<128, 128, 0, stream>>>(PART, m_w1, m_b1, m_w2, m_b2, TW, TI, SRWLOG);
    e1_kernel<<<dim3(5, 128, 2), 256, 0, stream>>>(FFT, ew1, eb1, TI, E1u);
    e23_kernel<<<dim3(128, 9), 512, 0, stream>>>(E1u, W2F, eb2, W3F, eb3, TI, TW, FINAL);
    pool_kernel<<<16384, 256, 0, stream>>>(FINAL, SRWLOG, out);
}

// Round 8
// 216.654 us; speedup vs baseline: 1.1469x; 1.1469x over previous
//
#include <hip/hip_runtime.h>

#define NFREQ 2049
#define L1LEN 1025
#define L2LEN 513

typedef short v8s  __attribute__((ext_vector_type(8)));
typedef float v16f __attribute__((ext_vector_type(16)));
typedef unsigned short ushort_t;
typedef unsigned int uint_t;

// ---------------- workspace layout (float offsets) ----------------
#define OFF_FFT     0ull          // 524544
#define OFF_TWID    524544ull     // 2048
#define OFF_PTW     526592ull     // 4352
#define OFF_WIN     530944ull     // 4096
#define OFF_PART    535040ull     // 540672
#define OFF_TW      1075712ull    // 256
#define OFF_TI      1075968ull    // 256 (ints)
#define OFF_SRWLOG  1076224ull    // 256
#define OFF_W2HF    1076480ull    // 5120  (ushort 10240, fragment-packed)
#define OFF_W2LF    1081600ull    // 5120
#define OFF_W2F     1086720ull    // 163840 (ushort 327680, fragment-packed)
#define OFF_W3F     1250560ull    // 196608 (ushort 393216, fragment-packed)
#define OFF_A       1447168ull    // FINAL f32 [b][o][q] (8404992) -- old E1u region (e1 fused away)
#define OFF_E2U     9852160ull    // E2u[2] (ushort 2*8404992), layout [k][b][q][c]
// total 18,257,152 floats ~ 69.6 MiB

#define E2U_K_STRIDE 8404992      // ushort elements per k (128*513*128)

__device__ __forceinline__ float relu_f(float x) { return fmaxf(x, 0.0f); }
__device__ __forceinline__ int   rfl_i(int v)   { return __builtin_amdgcn_readfirstlane(v); }
__device__ __forceinline__ float rfl_f(float v) { return __uint_as_float((unsigned)__builtin_amdgcn_readfirstlane((int)__float_as_uint(v))); }
__device__ __forceinline__ ushort_t f2bf(float x) {
    unsigned u = __float_as_uint(x);
    unsigned r = (u + 0x7FFFu + ((u >> 16) & 1u)) >> 16;   // RNE
    return (ushort_t)r;
}
__device__ __forceinline__ float bf2f(ushort_t h) { return __uint_as_float(((unsigned)h) << 16); }

// ---------------- init: tables + zero aux + fragment-pack weights ----------------
__global__ void init_kernel(float* SRWLOG, float* TWID, float* PTW, float* WIN,
                            ushort_t* W2HF, ushort_t* W2LF, ushort_t* W2F, ushort_t* W3F,
                            const float* g_w2, const float* ew2, const float* ew3) {
    const float PI = 3.14159265358979323846f;
    int tid = blockIdx.x * blockDim.x + threadIdx.x;
    int stride = gridDim.x * blockDim.x;
    for (int i = tid; i < 16; i += stride) SRWLOG[i] = 0.0f;
    for (int j = tid; j < 1024; j += stride) {
        float a = PI * (float)j / 1024.0f;
        TWID[2 * j] = cosf(a);
        TWID[2 * j + 1] = -sinf(a);
    }
    for (int k = tid; k < 2049; k += stride) {
        float a = PI * (float)k / 2048.0f;
        PTW[2 * k] = cosf(a);
        PTW[2 * k + 1] = sinf(a);
    }
    for (int n = tid; n < 4096; n += stride) {
        WIN[n] = 0.5f * (1.0f - cosf(2.0f * PI * (float)n / 4096.0f));
    }
    // g_w2 (64,32,5) -> W2HF/W2LF frag id=((t5*2+tile)*2+ks)
    for (int i = tid; i < 10240; i += stride) {
        int j = i & 7;
        int lane = (i >> 3) & 63;
        int ks = (i >> 9) & 1;
        int tile = (i >> 10) & 1;
        int t = i >> 11;
        int o = tile * 32 + (lane & 31);
        int c = ks * 16 + (lane >> 5) * 8 + j;
        float w = g_w2[o * 160 + c * 5 + t];
        ushort_t h = f2bf(w);
        W2HF[i] = h;
        W2LF[i] = f2bf(w - bf2f(h));
    }
    // ew2 (8,128,64,5) -> W2F frag id=(((e*5+t5)*4+w)*4+ks)
    for (int i = tid; i < 327680; i += stride) {
        int j = i & 7;
        int lane = (i >> 3) & 63;
        int ks = (i >> 9) & 3;
        int w = (i >> 11) & 3;
        int t = (i >> 13) % 5;
        int e = i / 40960;
        int o = w * 32 + (lane & 31);
        int c = ks * 16 + (lane >> 5) * 8 + j;
        W2F[i] = f2bf(ew2[((e * 128 + o) * 64 + c) * 5 + t]);
    }
    // ew3 (8,128,128,3) -> W3F frag id=(((e*3+t3)*4+w)*8+ks)
    for (int i = tid; i < 393216; i += stride) {
        int j = i & 7;
        int lane = (i >> 3) & 63;
        int ks = (i >> 9) & 7;
        int w = (i >> 12) & 3;
        int t = (i >> 14) % 3;
        int e = i / 49152;
        int o = w * 32 + (lane & 31);
        int c = ks * 16 + (lane >> 5) * 8 + j;
        W3F[i] = f2bf(ew3[((e * 128 + o) * 128 + c) * 3 + t]);
    }
}

// ---------------- windowed rfft(4096) via 2048-pt complex FFT (1024 threads) ----------------
__global__ __launch_bounds__(1024) void fft_kernel(const float* __restrict__ x,
                                                   const float* __restrict__ TWID,
                                                   const float* __restrict__ PTW,
                                                   const float* __restrict__ WIN,
                                                   float* __restrict__ FFT) {
    __shared__ float re[2048];
    __shared__ float im[2048];
    int b = blockIdx.x, t = threadIdx.x;
    const float* xb = x + b * 4096;
    for (int i = t; i < 2048; i += 1024) {
        int j = (int)(__brev((unsigned)i) >> 21);   // 11-bit reversal
        re[i] = xb[2 * j] * WIN[2 * j];
        im[i] = xb[2 * j + 1] * WIN[2 * j + 1];
    }
    for (int s = 1; s <= 11; ++s) {
        __syncthreads();
        int half = 1 << (s - 1);
        int shift = 11 - s;
        int bf = t;
        {
            int grp = bf >> (s - 1);
            int pos = bf & (half - 1);
            int i1 = (grp << s) + pos;
            int i2 = i1 + half;
            int j = pos << shift;
            float wr = TWID[2 * j], wi = TWID[2 * j + 1];
            float ar = re[i2], ai = im[i2];
            float tr = wr * ar - wi * ai;
            float ti = wr * ai + wi * ar;
            float br = re[i1], bi = im[i1];
            re[i2] = br - tr; im[i2] = bi - ti;
            re[i1] = br + tr; im[i1] = bi + ti;
        }
    }
    __syncthreads();
    const float scale = 1.0f / 64.0f;
    for (int k = t; k <= 2048; k += 1024) {
        int k1 = k & 2047;
        int k2 = (2048 - k) & 2047;
        float zr = re[k1], zi = im[k1];
        float yr = re[k2], yi = im[k2];
        float Er = 0.5f * (zr + yr), Ei = 0.5f * (zi - yi);
        float Or = 0.5f * (zi + yi), Oi = 0.5f * (yr - zr);
        float c2 = PTW[2 * k], s3 = PTW[2 * k + 1];
        FFT[b * 4098 + k]        = (Er + c2 * Or + s3 * Oi) * scale;
        FFT[b * 4098 + 2049 + k] = (Ei + c2 * Oi - s3 * Or) * scale;
    }
}

// ---------------- fused gate conv1 + conv2 (split-precision MFMA) + partial mean-pool ----------------
__global__ __launch_bounds__(256) void g12_kernel(const float* __restrict__ FFT,
                                                  const float* __restrict__ g_w1, const float* __restrict__ g_b1,
                                                  const ushort_t* __restrict__ W2HF, const ushort_t* __restrict__ W2LF,
                                                  const float* __restrict__ g_b2,
                                                  float* __restrict__ PART) {
    __shared__ float fx[2][72];
    __shared__ float w1S[320];
    __shared__ float b1S[32];
    __shared__ __align__(16) char un[17408];
    ushort_t (*xh)[40] = (ushort_t (*)[40])un;            // [68][40] = 5440B
    ushort_t (*xl)[40] = (ushort_t (*)[40])(un + 5440);   // [68][40] = 5440B
    float (*red)[68]  = (float (*)[68])un;                // [64][68] = 17408B (aliases xh/xl after MFMA)
    int b = blockIdx.y;
    int q0 = blockIdx.x * 64;
    int t = threadIdx.x;
    for (int i = t; i < 352; i += 256) {
        if (i < 320) w1S[i] = g_w1[i];
        else b1S[i - 320] = g_b1[i - 320];
    }
    {
        const float* fb = FFT + b * 4098;
        for (int i = t; i < 144; i += 256) {
            int ch = i / 72, u = i % 72;
            int P = q0 - 4 + u;
            fx[ch][u] = (P >= 0 && P < NFREQ) ? fb[ch * NFREQ + P] : 0.0f;
        }
    }
    __syncthreads();
    // ---- conv1: 17 row-groups x 32 ch; weights in regs; window via float4 ----
    {
        int c = t & 31;
        float bias = b1S[c];
        float wr[10];
        #pragma unroll
        for (int j = 0; j < 10; ++j) wr[j] = w1S[c * 10 + j];
        for (int i = t; i < 544; i += 256) {
            int g4 = (i >> 5) << 2;                       // base row, multiple of 4
            float4 x00 = *(const float4*)&fx[0][g4];
            float4 x01 = *(const float4*)&fx[0][g4 + 4];
            float4 x10 = *(const float4*)&fx[1][g4];
            float4 x11 = *(const float4*)&fx[1][g4 + 4];
            float xa[8] = {x00.x, x00.y, x00.z, x00.w, x01.x, x01.y, x01.z, x01.w};
            float xb_[8] = {x10.x, x10.y, x10.z, x10.w, x11.x, x11.y, x11.z, x11.w};
            #pragma unroll
            for (int rr = 0; rr < 4; ++rr) {
                int row = g4 + rr;
                int pos = q0 - 2 + row;
                ushort_t h = 0, l = 0;
                if (pos >= 0 && pos < NFREQ) {
                    float a = bias;
                    #pragma unroll
                    for (int tt = 0; tt < 5; ++tt) a = fmaf(xa[rr + tt], wr[tt], a);
                    #pragma unroll
                    for (int tt = 0; tt < 5; ++tt) a = fmaf(xb_[rr + tt], wr[5 + tt], a);
                    a = relu_f(a);
                    h = f2bf(a);
                    l = f2bf(a - bf2f(h));
                }
                xh[row][c] = h;
                xl[row][c] = l;
            }
        }
    }
    __syncthreads();
    int lane = t & 63;
    int w = rfl_i(t >> 6);
    int tile = w & 1;
    int qh = w >> 1;
    int n = lane & 31;
    int kg = lane >> 5;
    v16f acc;
    #pragma unroll
    for (int i = 0; i < 16; ++i) acc[i] = 0.0f;
    #pragma unroll
    for (int t5 = 0; t5 < 5; ++t5) {
        int row = qh * 32 + n + t5;
        #pragma unroll
        for (int ks = 0; ks < 2; ++ks) {
            int c0 = ks * 16 + kg * 8;
            v8s Ah = *(const v8s*)(W2HF + (((t5 * 2 + tile) * 2 + ks) << 9) + lane * 8);
            v8s Al = *(const v8s*)(W2LF + (((t5 * 2 + tile) * 2 + ks) << 9) + lane * 8);
            v8s Bh = *(const v8s*)&xh[row][c0];
            v8s Bl = *(const v8s*)&xl[row][c0];
            acc = __builtin_amdgcn_mfma_f32_32x32x16_bf16(Ah, Bh, acc, 0, 0, 0);
            acc = __builtin_amdgcn_mfma_f32_32x32x16_bf16(Ah, Bl, acc, 0, 0, 0);
            acc = __builtin_amdgcn_mfma_f32_32x32x16_bf16(Al, Bh, acc, 0, 0, 0);
        }
    }
    __syncthreads();   // xh/xl dead -> red
    {
        int q = q0 + qh * 32 + n;
        bool valid = (q < NFREQ);
        #pragma unroll
        for (int r = 0; r < 16; ++r) {
            int m = (r & 3) + 8 * (r >> 2) + 4 * kg;
            int o = tile * 32 + m;
            red[o][qh * 32 + n] = valid ? relu_f(acc[r] + g_b2[o]) : 0.0f;
        }
    }
    __syncthreads();
    // ---- transpose reduce: thread t sums red[t>>2][(t&3)*16 .. +16) ----
    {
        int o = t >> 2;
        int qq = t & 3;
        float s = 0.0f;
        #pragma unroll
        for (int u = 0; u < 4; ++u) {
            float4 vv = *(const float4*)&red[o][qq * 16 + u * 4];
            s += vv.x + vv.y + vv.z + vv.w;
        }
        s += __shfl_xor(s, 1, 64);
        s += __shfl_xor(s, 2, 64);
        if (qq == 0) PART[(b * 64 + o) * 66 + blockIdx.x] = s;
    }
}

// ---------------- router MLP + softmax + top2 + aux partials ----------------
__global__ __launch_bounds__(128) void mlp_kernel(const float* __restrict__ PART,
                                                  const float* __restrict__ m_w1, const float* __restrict__ m_b1,
                                                  const float* __restrict__ m_w2, const float* __restrict__ m_b2,
                                                  float* TW, int* TI, float* SRWLOG) {
    __shared__ float pooledS[64];
    __shared__ float hid[128];
    __shared__ float lgS[8];
    __shared__ float rwS[8];
    int b = blockIdx.x, t = threadIdx.x;
    if (t < 64) {
        float s = 0.0f;
        const float* pp = PART + (b * 64 + t) * 66;
        for (int blk = 0; blk < 33; ++blk) s += pp[blk];
        pooledS[t] = s;
    }
    __syncthreads();
    const float inv = 1.0f / 2049.0f;
    {
        float h = m_b1[t];
        for (int c = 0; c < 64; ++c)
            h = fmaf(pooledS[c] * inv, m_w1[t * 64 + c], h);
        hid[t] = relu_f(h);
    }
    __syncthreads();
    if (t < 8) {
        float lg = m_b2[t];
        for (int j = 0; j < 128; ++j) lg = fmaf(hid[j], m_w2[t * 128 + j], lg);
        lgS[t] = lg;
    }
    __syncthreads();
    if (t == 0) {
        float mx = lgS[0];
        for (int e = 1; e < 8; ++e) mx = fmaxf(mx, lgS[e]);
        float s = 0.0f, ex[8];
        for (int e = 0; e < 8; ++e) { ex[e] = expf(lgS[e] - mx); s += ex[e]; }
        for (int e = 0; e < 8; ++e) rwS[e] = ex[e] / s;
        int i1 = 0;
        for (int e = 1; e < 8; ++e) if (rwS[e] > rwS[i1]) i1 = e;
        int i2 = (i1 == 0) ? 1 : 0;
        for (int e = 0; e < 8; ++e) if (e != i1 && rwS[e] > rwS[i2]) i2 = e;
        float t0 = rwS[i1], t1 = rwS[i2], sm = t0 + t1;
        TW[b * 2] = t0 / sm; TW[b * 2 + 1] = t1 / sm;
        TI[b * 2] = i1; TI[b * 2 + 1] = i2;
    }
    __syncthreads();
    if (t < 8) {
        atomicAdd(&SRWLOG[t], rwS[t]);
        atomicAdd(&SRWLOG[8 + t], lgS[t]);
    }
}

// ---------------- FUSED expert conv1 + conv2 (MFMA): FFT -> E2 [k][b][q][c] ----------------
// r8: e1 fused into e2. Block stages 2.1KB FFT window (vs 17KB E1u), conv1 weights
// in regs (c = lane; fxs reads wave-broadcast; xe/xo writes 2-way-free), conv1
// recomputed inline with e1's EXACT FMA order (bit-identical bf16). Removes the
// 33.6MB E1u write + 39MB read + one launch. ~1.16x conv1 duplication across q-tiles.
__global__ __launch_bounds__(256) void e12_kernel(const float* __restrict__ FFT,
                                                  const float* __restrict__ ew1, const float* __restrict__ eb1,
                                                  const ushort_t* __restrict__ W2F, const float* __restrict__ eb2,
                                                  const int* __restrict__ TI, ushort_t* __restrict__ E2u) {
    __shared__ float fxs[2][272];                          // FFT positions 4q0-7 .. 4q0+264
    __shared__ __align__(16) char sm2[19008];
    ushort_t (*xe)[72] = (ushort_t (*)[72])sm2;            // [66][72] E1 even positions
    ushort_t (*xo)[72] = (ushort_t (*)[72])(sm2 + 9504);   // [66][72] E1 odd positions
    ushort_t (*oT)[136] = (ushort_t (*)[136])sm2;          // [64][136] (reuses sm2 after MFMA)
    int b = blockIdx.x;
    int k = blockIdx.z;
    int q0 = blockIdx.y * 64;
    int t = threadIdx.x;
    int e = rfl_i(TI[b * 2 + k]);
    // ---- stage FFT window ----
    {
        const float* fb = FFT + b * 4098;
        for (int i = t; i < 544; i += 256) {
            int ch = i / 272, off = i - ch * 272;
            int P = 4 * q0 - 7 + off;
            fxs[ch][off] = (P >= 0 && P < NFREQ) ? fb[ch * NFREQ + P] : 0.0f;
        }
    }
    // ---- conv1 weights to regs (c fixed per thread) ----
    int c = t & 63;
    float w1r[14];
    #pragma unroll
    for (int j = 0; j < 14; ++j) w1r[j] = ew1[(e * 64 + c) * 14 + j];
    float b1r = eb1[e * 64 + c];
    __syncthreads();
    // ---- conv1: wave g handles rows r == g (mod 4); 33 rows x 64 ch per wave ----
    {
        int g0 = t >> 6;
        for (int r = g0; r < 132; r += 4) {
            int p = 2 * q0 - 2 + r;                        // E1 position
            ushort_t val = 0;
            if (p >= 0 && p < L1LEN) {
                float a = b1r;
                #pragma unroll
                for (int tt = 0; tt < 7; ++tt) a = fmaf(fxs[0][2 * r + tt], w1r[tt], a);
                #pragma unroll
                for (int tt = 0; tt < 7; ++tt) a = fmaf(fxs[1][2 * r + tt], w1r[7 + tt], a);
                val = f2bf(relu_f(a));
            }
            if (r & 1) xo[r >> 1][c] = val;
            else       xe[r >> 1][c] = val;
        }
    }
    __syncthreads();
    int lane = t & 63;
    int w = rfl_i(t >> 6);
    int n = lane & 31;
    int kg = lane >> 5;
    v16f acc0, acc1;
    #pragma unroll
    for (int i = 0; i < 16; ++i) { acc0[i] = 0.0f; acc1[i] = 0.0f; }
    #pragma unroll
    for (int t5 = 0; t5 < 5; ++t5) {
        int roff = t5 >> 1;
        const ushort_t (*sel)[72] = (t5 & 1) ? xo : xe;
        const ushort_t* wfrag = W2F + ((((e * 5 + t5) * 4 + w) * 4) << 9) + lane * 8;
        #pragma unroll
        for (int ks = 0; ks < 4; ++ks) {
            int c0 = ks * 16 + kg * 8;
            v8s a = *(const v8s*)(wfrag + (ks << 9));
            v8s b0 = *(const v8s*)&sel[n + roff][c0];
            v8s b1 = *(const v8s*)&sel[n + 32 + roff][c0];
            acc0 = __builtin_amdgcn_mfma_f32_32x32x16_bf16(a, b0, acc0, 0, 0, 0);
            acc1 = __builtin_amdgcn_mfma_f32_32x32x16_bf16(a, b1, acc1, 0, 0, 0);
        }
    }
    __syncthreads();   // xe/xo dead -> oT
    #pragma unroll
    for (int g = 0; g < 4; ++g) {
        int ob = w * 32 + 8 * g + 4 * kg;    // 4 consecutive o per C-frag quad
        uint_t p00 = (uint_t)f2bf(relu_f(acc0[4 * g + 0] + eb2[e * 128 + ob + 0]))
                   | ((uint_t)f2bf(relu_f(acc0[4 * g + 1] + eb2[e * 128 + ob + 1])) << 16);
        uint_t p01 = (uint_t)f2bf(relu_f(acc0[4 * g + 2] + eb2[e * 128 + ob + 2]))
                   | ((uint_t)f2bf(relu_f(acc0[4 * g + 3] + eb2[e * 128 + ob + 3])) << 16);
        uint_t p10 = (uint_t)f2bf(relu_f(acc1[4 * g + 0] + eb2[e * 128 + ob + 0]))
                   | ((uint_t)f2bf(relu_f(acc1[4 * g + 1] + eb2[e * 128 + ob + 1])) << 16);
        uint_t p11 = (uint_t)f2bf(relu_f(acc1[4 * g + 2] + eb2[e * 128 + ob + 2]))
                   | ((uint_t)f2bf(relu_f(acc1[4 * g + 3] + eb2[e * 128 + ob + 3])) << 16);
        uint2 v0; v0.x = p00; v0.y = p01;
        uint2 v1; v1.x = p10; v1.y = p11;
        *(uint2*)&oT[n][ob]      = v0;
        *(uint2*)&oT[32 + n][ob] = v1;
    }
    __syncthreads();
    ushort_t* E2k = E2u + (size_t)k * E2U_K_STRIDE;
    for (int i = t; i < 64 * 16; i += 256) {   // 16B chunks: 64 rows x 128 ushorts
        int qq = i >> 4, c8 = (i & 15) * 8;
        int q = q0 + qq;
        if (q < L2LEN)
            *(uint4*)(E2k + ((size_t)b * L2LEN + q) * 128 + c8) = *(const uint4*)&oT[qq][c8];
    }
}

// ---------------- expert conv3 (MFMA only): writes FINAL f32 [b][o][q] ----------------
// r5 structure: 256 thr / 4 waves, wave = ow, both q-halves per wave (weight reuse);
// k=1 staging issued into regs before k=0 compute (T14 issue-early / write-late).
__global__ __launch_bounds__(256) void e3_kernel(const ushort_t* __restrict__ E2u,
                                                 const ushort_t* __restrict__ W3F, const float* __restrict__ eb3,
                                                 const int* __restrict__ TI, const float* __restrict__ TW,
                                                 float* __restrict__ FINAL) {
    __shared__ __align__(16) ushort_t xT[2][66][136];   // 35904B
    int b = blockIdx.x;
    int q0 = blockIdx.y * 64;
    int t = threadIdx.x;
    int lane = t & 63;
    int ow = rfl_i(t >> 6);       // 4 waves, one o-tile each
    int n = lane & 31;
    int kg = lane >> 5;
    int e0  = rfl_i(TI[b * 2]);
    int e1_ = rfl_i(TI[b * 2 + 1]);
    float wk0 = rfl_f(TW[b * 2]);
    float wk1 = rfl_f(TW[b * 2 + 1]);
    // ---- stage k=0 to LDS ----
    for (int i = t; i < 1056; i += 256) {
        int row = i >> 4, c8 = (i & 15) * 8;
        int pos = q0 - 1 + row;
        uint4 v; v.x = 0u; v.y = 0u; v.z = 0u; v.w = 0u;
        if (pos >= 0 && pos < L2LEN)
            v = *(const uint4*)(E2u + ((size_t)b * L2LEN + pos) * 128 + c8);
        *(uint4*)&xT[0][row][c8] = v;
    }
    __syncthreads();
    // ---- issue k=1 staging loads into regs ----
    uint4 st[5];
    #pragma unroll
    for (int j = 0; j < 5; ++j) {
        int i = t + j * 256;
        uint4 v; v.x = 0u; v.y = 0u; v.z = 0u; v.w = 0u;
        if (i < 1056) {
            int row = i >> 4, c8 = (i & 15) * 8;
            int pos = q0 - 1 + row;
            if (pos >= 0 && pos < L2LEN)
                v = *(const uint4*)(E2u + (size_t)E2U_K_STRIDE + ((size_t)b * L2LEN + pos) * 128 + c8);
        }
        st[j] = v;
    }
    float res0[16], res1[16];
    #pragma unroll
    for (int i = 0; i < 16; ++i) { res0[i] = 0.0f; res1[i] = 0.0f; }
    // ---- compute k=0 ----
    {
        v16f a0, a1;
        #pragma unroll
        for (int i = 0; i < 16; ++i) { a0[i] = 0.0f; a1[i] = 0.0f; }
        #pragma unroll
        for (int t3 = 0; t3 < 3; ++t3) {
            const ushort_t* wfrag = W3F + ((((e0 * 3 + t3) * 4 + ow) * 8) << 9) + lane * 8;
            #pragma unroll
            for (int ks = 0; ks < 8; ++ks) {
                int c0 = ks * 16 + kg * 8;
                v8s a = *(const v8s*)(wfrag + (ks << 9));
                v8s b0 = *(const v8s*)&xT[0][n + t3][c0];
                v8s b1 = *(const v8s*)&xT[0][32 + n + t3][c0];
                a0 = __builtin_amdgcn_mfma_f32_32x32x16_bf16(a, b0, a0, 0, 0, 0);
                a1 = __builtin_amdgcn_mfma_f32_32x32x16_bf16(a, b1, a1, 0, 0, 0);
            }
        }
        #pragma unroll
        for (int r = 0; r < 16; ++r) {
            int m = (r & 3) + 8 * (r >> 2) + 4 * kg;
            float bias = eb3[e0 * 128 + ow * 32 + m];
            res0[r] += relu_f(a0[r] + bias) * wk0;
            res1[r] += relu_f(a1[r] + bias) * wk0;
        }
    }
    // ---- write k=1 staging regs -> LDS, barrier ----
    #pragma unroll
    for (int j = 0; j < 5; ++j) {
        int i = t + j * 256;
        if (i < 1056) {
            int row = i >> 4, c8 = (i & 15) * 8;
            *(uint4*)&xT[1][row][c8] = st[j];
        }
    }
    __syncthreads();
    // ---- compute k=1 ----
    {
        v16f a0, a1;
        #pragma unroll
        for (int i = 0; i < 16; ++i) { a0[i] = 0.0f; a1[i] = 0.0f; }
        #pragma unroll
        for (int t3 = 0; t3 < 3; ++t3) {
            const ushort_t* wfrag = W3F + ((((e1_ * 3 + t3) * 4 + ow) * 8) << 9) + lane * 8;
            #pragma unroll
            for (int ks = 0; ks < 8; ++ks) {
                int c0 = ks * 16 + kg * 8;
                v8s a = *(const v8s*)(wfrag + (ks << 9));
                v8s b0 = *(const v8s*)&xT[1][n + t3][c0];
                v8s b1 = *(const v8s*)&xT[1][32 + n + t3][c0];
                a0 = __builtin_amdgcn_mfma_f32_32x32x16_bf16(a, b0, a0, 0, 0, 0);
                a1 = __builtin_amdgcn_mfma_f32_32x32x16_bf16(a, b1, a1, 0, 0, 0);
            }
        }
        #pragma unroll
        for (int r = 0; r < 16; ++r) {
            int m = (r & 3) + 8 * (r >> 2) + 4 * kg;
            float bias = eb3[e1_ * 128 + ow * 32 + m];
            res0[r] += relu_f(a0[r] + bias) * wk1;
            res1[r] += relu_f(a1[r] + bias) * wk1;
        }
    }
    // ---- store FINAL[b][o][q] directly from C-frags ----
    float* Fb = FINAL + (size_t)b * 128 * 513;
    int qA = q0 + n;
    int qB = q0 + 32 + n;
    #pragma unroll
    for (int r = 0; r < 16; ++r) {
        int m = (r & 3) + 8 * (r >> 2) + 4 * kg;
        int o = ow * 32 + m;
        if (qA < L2LEN) Fb[o * 513 + qA] = res0[r];
        if (qB < L2LEN) Fb[o * 513 + qB] = res1[r];
    }
}

// ---------------- adaptive max-pool (one thread per output) + aux epilogue ----------------
__global__ __launch_bounds__(256) void pool_kernel(const float* __restrict__ FINAL,
                                                   const float* __restrict__ SRWLOG,
                                                   float* __restrict__ out) {
    if (blockIdx.x == 0 && threadIdx.x == 0) {
        float a = 0.0f;
        for (int e = 0; e < 8; ++e)
            a += (SRWLOG[e] / 128.0f) * (SRWLOG[8 + e] / 128.0f);
        out[4194304] = 0.01f * 8.0f * a;
    }
    int idx = blockIdx.x * 256 + threadIdx.x;     // 4,194,304 outputs
    int j = idx & 255;
    int row = idx >> 8;                           // b*128 + o
    const float* f = FINAL + (size_t)row * 513;
    int s = (513 * j) >> 8;
    int e_ = (513 * (j + 1) + 255) >> 8;          // <= 513
    float m = f[s];
    for (int p = s + 1; p < e_; ++p) m = fmaxf(m, f[p]);
    out[idx] = m;
}

extern "C" void kernel_launch(void* const* d_in, const int* in_sizes, int n_in,
                              void* d_out, int out_size, void* d_ws, size_t ws_size,
                              hipStream_t stream) {
    const float* x    = (const float*)d_in[0];
    const float* g_w1 = (const float*)d_in[1];
    const float* g_b1 = (const float*)d_in[2];
    const float* g_w2 = (const float*)d_in[3];
    const float* g_b2 = (const float*)d_in[4];
    const float* m_w1 = (const float*)d_in[5];
    const float* m_b1 = (const float*)d_in[6];
    const float* m_w2 = (const float*)d_in[7];
    const float* m_b2 = (const float*)d_in[8];
    const float* ew1  = (const float*)d_in[9];
    const float* eb1  = (const float*)d_in[10];
    const float* ew2  = (const float*)d_in[11];
    const float* eb2  = (const float*)d_in[12];
    const float* ew3  = (const float*)d_in[13];
    const float* eb3  = (const float*)d_in[14];

    float* ws     = (float*)d_ws;
    float* FFT    = ws + OFF_FFT;
    float* TWID   = ws + OFF_TWID;
    float* PTW    = ws + OFF_PTW;
    float* WIN    = ws + OFF_WIN;
    float* PART   = ws + OFF_PART;
    float* TW     = ws + OFF_TW;
    int*   TI     = (int*)(ws + OFF_TI);
    float* SRWLOG = ws + OFF_SRWLOG;
    ushort_t* W2HF = (ushort_t*)(ws + OFF_W2HF);
    ushort_t* W2LF = (ushort_t*)(ws + OFF_W2LF);
    ushort_t* W2F  = (ushort_t*)(ws + OFF_W2F);
    ushort_t* W3F  = (ushort_t*)(ws + OFF_W3F);
    float* FINAL  = ws + OFF_A;                 // old E1u region (e1 fused away)
    ushort_t* E2u = (ushort_t*)(ws + OFF_E2U);
    float* out    = (float*)d_out;

    init_kernel<<<512, 256, 0, stream>>>(SRWLOG, TWID, PTW, WIN, W2HF, W2LF, W2F, W3F, g_w2, ew2, ew3);
    fft_kernel<<<128, 1024, 0, stream>>>(x, TWID, PTW, WIN, FFT);
    g12_kernel<<<dim3(33, 128), 256, 0, stream>>>(FFT, g_w1, g_b1, W2HF, W2LF, g_b2, PART);
    mlp_kernel<<<128, 128, 0, stream>>>(PART, m_w1, m_b1, m_w2, m_b2, TW, TI, SRWLOG);
    e12_kernel<<<dim3(128, 9, 2), 256, 0, stream>>>(FFT, ew1, eb1, W2F, eb2, TI, E2u);
    e3_kernel<<<dim3(128, 9), 256, 0, stream>>>(E2u, W3F, eb3, TI, TW, FINAL);
    pool_kernel<<<16384, 256, 0, stream>>>(FINAL, SRWLOG, out);
}